// Round 19
// baseline (244.574 us; speedup 1.0000x reference)
//
#include <hip/hip_runtime.h>

#define NN 100000
#define EE 500000
#define FIN 64
#define HH 128
#define BN_EPS 1e-5f
#define NB ((NN + 255) / 256)   // 391 scan blocks

typedef unsigned short u16;
typedef unsigned long long u64;
typedef short bf16x8 __attribute__((ext_vector_type(8)));
typedef float f32x4 __attribute__((ext_vector_type(4)));

__device__ __forceinline__ u16 f2bf(float f) {
    unsigned int u = __float_as_uint(f);
    u = (u + 0x7FFFu + ((u >> 16) & 1u)) >> 16;   // round-to-nearest-even
    return (u16)u;
}
__device__ __forceinline__ float bf2f(u16 u) {
    return __uint_as_float((unsigned int)u << 16);
}
__device__ __forceinline__ int2 ldnt2(const int2* p) {
    u64 v = __builtin_nontemporal_load((const u64*)p);
    int2 r;
    r.x = (int)(unsigned)(v & 0xFFFFFFFFull);
    r.y = (int)(unsigned)(v >> 32);
    return r;
}
__device__ __forceinline__ void fma8(float* a, uint4 s, float w) {
    a[0] += bf2f((u16)(s.x & 0xFFFF)) * w;
    a[1] += bf2f((u16)(s.x >> 16))    * w;
    a[2] += bf2f((u16)(s.y & 0xFFFF)) * w;
    a[3] += bf2f((u16)(s.y >> 16))    * w;
    a[4] += bf2f((u16)(s.z & 0xFFFF)) * w;
    a[5] += bf2f((u16)(s.z >> 16))    * w;
    a[6] += bf2f((u16)(s.w & 0xFFFF)) * w;
    a[7] += bf2f((u16)(s.w >> 16))    * w;
}
__device__ __forceinline__ uint4 pack8(const float* a) {
    uint4 o;
    o.x = (unsigned)f2bf(a[0]) | ((unsigned)f2bf(a[1]) << 16);
    o.y = (unsigned)f2bf(a[2]) | ((unsigned)f2bf(a[3]) << 16);
    o.z = (unsigned)f2bf(a[4]) | ((unsigned)f2bf(a[5]) << 16);
    o.w = (unsigned)f2bf(a[6]) | ((unsigned)f2bf(a[7]) << 16);
    return o;
}

// ---------------- setup: x->bf16, zero deg, all W -> Wt bf16 transposed ----------------

__global__ __launch_bounds__(256) void setup_kernel(const float* __restrict__ x,
                                                    u16* __restrict__ xb,
                                                    int* __restrict__ deg,
                                                    const float* __restrict__ W1,
                                                    const float* __restrict__ W2,
                                                    const float* __restrict__ W3,
                                                    u16* __restrict__ wt1,
                                                    u16* __restrict__ wt2,
                                                    u16* __restrict__ wt3) {
    int i = blockIdx.x * 256 + threadIdx.x;
    if (i < NN) deg[i] = 0;
    if (i < HH * FIN) {
        int n = i / FIN, k = i - n * FIN;
        wt1[i] = f2bf(W1[(size_t)k * HH + n]);
    }
    if (i < HH * HH) {
        int n = i >> 7, k = i & 127;
        wt2[i] = f2bf(W2[(size_t)k * HH + n]);
        wt3[i] = f2bf(W3[(size_t)k * HH + n]);
    }
    if (i < NN * FIN / 8) {
        float4 f0 = ((const float4*)x)[i * 2];
        float4 f1 = ((const float4*)x)[i * 2 + 1];
        uint4 o;
        o.x = (unsigned)f2bf(f0.x) | ((unsigned)f2bf(f0.y) << 16);
        o.y = (unsigned)f2bf(f0.z) | ((unsigned)f2bf(f0.w) << 16);
        o.z = (unsigned)f2bf(f1.x) | ((unsigned)f2bf(f1.y) << 16);
        o.w = (unsigned)f2bf(f1.z) | ((unsigned)f2bf(f1.w) << 16);
        ((uint4*)xb)[i] = o;
    }
}

// ---------------- CSR build ----------------

__global__ __launch_bounds__(256) void hist_kernel(const int* __restrict__ dst,
                                                   int* __restrict__ deg) {
    int e = blockIdx.x * 256 + threadIdx.x;
    if (e < EE) atomicAdd(&deg[__builtin_nontemporal_load(&dst[e])], 1);
}

__global__ __launch_bounds__(256) void scan1_kernel(const int* __restrict__ deg,
                                                    int* __restrict__ rowstart,
                                                    int* __restrict__ blksum,
                                                    float* __restrict__ dinv) {
    __shared__ int s[256];
    int t = threadIdx.x;
    int i = blockIdx.x * 256 + t;
    int v = (i < NN) ? deg[i] : 0;
    if (i < NN) dinv[i] = rsqrtf((float)v + 1.0f);
    s[t] = v;
    __syncthreads();
    #pragma unroll
    for (int off = 1; off < 256; off <<= 1) {
        int add = (t >= off) ? s[t - off] : 0;
        __syncthreads();
        s[t] += add;
        __syncthreads();
    }
    if (i < NN) rowstart[i] = s[t] - v;
    if (t == 255) blksum[blockIdx.x] = s[255];
}

__global__ __launch_bounds__(512) void scan23_kernel(int* __restrict__ rowstart,
                                                     const int* __restrict__ blksum,
                                                     int* __restrict__ cursor) {
    __shared__ int s[512];
    __shared__ int ex[512];
    int t = threadIdx.x;
    int vv = (t < NB) ? blksum[t] : 0;
    s[t] = vv;
    __syncthreads();
    #pragma unroll
    for (int off = 1; off < 512; off <<= 1) {
        int add = (t >= off) ? s[t - off] : 0;
        __syncthreads();
        s[t] += add;
        __syncthreads();
    }
    ex[t] = s[t] - vv;
    __syncthreads();
    int i = blockIdx.x * 512 + t;
    if (i < NN) {
        int r = rowstart[i] + ex[i >> 8];
        rowstart[i] = r;
        cursor[i] = r;
    }
    if (i == 0) rowstart[NN] = EE;
}

__global__ __launch_bounds__(256) void fill_kernel(const int* __restrict__ src,
                                                   const int* __restrict__ dst,
                                                   const float* __restrict__ dinv,
                                                   int* __restrict__ cursor,
                                                   int2* __restrict__ csr) {
    int e = blockIdx.x * 256 + threadIdx.x;
    if (e >= EE) return;
    int s = __builtin_nontemporal_load(&src[e]);
    int d = __builtin_nontemporal_load(&dst[e]);
    float nm = dinv[s] * dinv[d];
    int pos = atomicAdd(&cursor[d], 1);
    csr[pos] = make_int2(s, __float_as_int(nm));   // L2-cached store (re-read 4x)
}

// ---------------- gather aggregation (bf16 in/out, fp32 accumulate) ----------------
// lane-parallel csr read + shfl broadcast; 16 row-gathers in flight per group.
// P(deg<=16) ~ 0.99997 -> one super-round for virtually all nodes.

__global__ __launch_bounds__(256) void agg128_kernel(const u16* __restrict__ x,
                                                     const int2* __restrict__ csr,
                                                     const int* __restrict__ rowstart,
                                                     const float* __restrict__ dinv,
                                                     u16* __restrict__ out) {
    int gid = blockIdx.x * 16 + (threadIdx.x >> 4);
    int lane = threadIdx.x & 15;
    if (gid >= NN) return;
    float sn = dinv[gid];
    sn *= sn;
    const uint4* xp = (const uint4*)x;   // row = 16 x uint4 (8 bf16 each)
    float a[8] = {0, 0, 0, 0, 0, 0, 0, 0};
    fma8(a, xp[(size_t)gid * 16 + lane], sn);
    int e0 = rowstart[gid], e1 = rowstart[gid + 1];
    for (int base = e0; base < e1; base += 16) {
        int rem = e1 - base;                         // >= 1
        int ci = base + ((lane < rem) ? lane : (rem - 1));
        int2 my = ldnt2(&csr[ci]);                   // lane j holds entry base+j
        float myw = (lane < rem) ? __int_as_float(my.y) : 0.0f;
        int myrow = my.x;
        uint4 s[16];
        #pragma unroll
        for (int j = 0; j < 16; j++) {
            int rj = __shfl(myrow, j, 16);
            s[j] = xp[(size_t)rj * 16 + lane];
        }
        #pragma unroll
        for (int j = 0; j < 16; j++) {
            float wj = __shfl(myw, j, 16);
            fma8(a, s[j], wj);
        }
    }
    ((uint4*)out)[(size_t)gid * 16 + lane] = pack8(a);
}

__global__ __launch_bounds__(256) void agg64_kernel(const u16* __restrict__ x,
                                                    const int2* __restrict__ csr,
                                                    const int* __restrict__ rowstart,
                                                    const float* __restrict__ dinv,
                                                    u16* __restrict__ out) {
    int gid = blockIdx.x * 32 + (threadIdx.x >> 3);
    int lane = threadIdx.x & 7;
    if (gid >= NN) return;
    float sn = dinv[gid];
    sn *= sn;
    const uint4* xp = (const uint4*)x;   // row = 8 x uint4 (8 bf16 each)
    float a[8] = {0, 0, 0, 0, 0, 0, 0, 0};
    fma8(a, xp[(size_t)gid * 8 + lane], sn);
    int e0 = rowstart[gid], e1 = rowstart[gid + 1];
    for (int base = e0; base < e1; base += 8) {
        int rem = e1 - base;
        int ci = base + ((lane < rem) ? lane : (rem - 1));
        int2 my = ldnt2(&csr[ci]);
        float myw = (lane < rem) ? __int_as_float(my.y) : 0.0f;
        int myrow = my.x;
        uint4 s[8];
        #pragma unroll
        for (int j = 0; j < 8; j++) {
            int rj = __shfl(myrow, j, 8);
            s[j] = xp[(size_t)rj * 8 + lane];
        }
        #pragma unroll
        for (int j = 0; j < 8; j++) {
            float wj = __shfl(myw, j, 8);
            fma8(a, s[j], wj);
        }
    }
    ((uint4*)out)[(size_t)gid * 8 + lane] = pack8(a);
}

// ---------------- MFMA GEMM + bias + BN(eval) + ReLU ----------------
// BM=128: 4 waves, each wave owns 32 rows (2x 16-row tiles) -> B-frags shared
// across both tiles. Epilogue via LDS -> coalesced uint4 stores (MODE<2).
// MODE 0: store C.  MODE 1: store C and zres[row] = dot(C_row, W4).
// MODE 2: no C store, no LDS; z[row] = dot(C_row, W4) + zres[row].

template<int K, int MODE>
__global__ __launch_bounds__(256) void gemm_bn_relu(const u16* __restrict__ A,
                                                    const u16* __restrict__ Wt,
                                                    const float* __restrict__ bias,
                                                    const float* __restrict__ g,
                                                    const float* __restrict__ be,
                                                    const float* __restrict__ m,
                                                    const float* __restrict__ v,
                                                    u16* __restrict__ out,
                                                    const float* __restrict__ W4,
                                                    float* __restrict__ zres,
                                                    float* __restrict__ z) {
    __shared__ u16 Csm[(MODE < 2) ? 128 * HH : 16];   // 32 KB when storing C

    int tid = threadIdx.x;
    int wave = tid >> 6;
    int lane = tid & 63;
    int lrow = lane & 15;
    int kgrp = lane >> 4;

    int blk0 = blockIdx.x * 128;
    int w0r = blk0 + wave * 32;            // wave's first row (2 tiles of 16)
    int ar0 = w0r + lrow;       if (ar0 >= NN) ar0 = NN - 1;
    int ar1 = w0r + 16 + lrow;  if (ar1 >= NN) ar1 = NN - 1;

    f32x4 acc[2][8];
    #pragma unroll
    for (int t = 0; t < 2; t++)
        #pragma unroll
        for (int ct = 0; ct < 8; ct++) acc[t][ct] = (f32x4){0.f, 0.f, 0.f, 0.f};

    #pragma unroll
    for (int kc = 0; kc < K / 32; kc++) {
        bf16x8 afr0 = *(const bf16x8*)&A[(size_t)ar0 * K + kc * 32 + kgrp * 8];
        bf16x8 afr1 = *(const bf16x8*)&A[(size_t)ar1 * K + kc * 32 + kgrp * 8];
        #pragma unroll
        for (int ct = 0; ct < 8; ct++) {
            bf16x8 bfr = *(const bf16x8*)&Wt[(size_t)(ct * 16 + lrow) * K + kc * 32 + kgrp * 8];
            acc[0][ct] = __builtin_amdgcn_mfma_f32_16x16x32_bf16(afr0, bfr, acc[0][ct], 0, 0, 0);
            acc[1][ct] = __builtin_amdgcn_mfma_f32_16x16x32_bf16(afr1, bfr, acc[1][ct], 0, 0, 0);
        }
    }

    // BN scale/shift for this lane's 8 columns (col = ct*16 + lrow)
    float sc[8], sh[8];
    #pragma unroll
    for (int ct = 0; ct < 8; ct++) {
        int col = ct * 16 + lrow;
        float s = g[col] * rsqrtf(v[col] + BN_EPS);
        sc[ct] = s;
        sh[ct] = (bias[col] - m[col]) * s + be[col];
    }

    float w4[8];
    if constexpr (MODE >= 1) {
        #pragma unroll
        for (int ct = 0; ct < 8; ct++) w4[ct] = W4[ct * 16 + lrow];
    }

    int rbase = kgrp * 4;   // C layout: row = tile0 + rbase + r, col = ct*16 + lrow
    #pragma unroll
    for (int t = 0; t < 2; t++) {
        #pragma unroll
        for (int r = 0; r < 4; r++) {
            int lr = wave * 32 + t * 16 + rbase + r;
            int row = blk0 + lr;
            float part = 0.0f;
            #pragma unroll
            for (int ct = 0; ct < 8; ct++) {
                float val = fmaxf(acc[t][ct][r] * sc[ct] + sh[ct], 0.0f);
                if constexpr (MODE < 2)
                    Csm[lr * HH + ct * 16 + lrow] = f2bf(val);
                if constexpr (MODE >= 1)
                    part += val * w4[ct];
            }
            if constexpr (MODE >= 1) {
                #pragma unroll
                for (int off = 1; off < 16; off <<= 1)
                    part += __shfl_xor(part, off, 16);
                if (lrow == 0 && row < NN) {
                    if constexpr (MODE == 1) zres[row] = part;
                    else                     z[row] = part + zres[row];
                }
            }
        }
    }

    if constexpr (MODE < 2) {
        __syncthreads();
        // coalesced writeback: 128 rows x 128 cols bf16 = 32 KB, uint4 x8 per thread
        #pragma unroll
        for (int it = 0; it < 8; it++) {
            int id = it * 256 + tid;
            int lr = id >> 4;
            int ch = id & 15;
            int row = blk0 + lr;
            if (row < NN)
                *(uint4*)&out[(size_t)row * HH + ch * 8] =
                    *(const uint4*)&Csm[lr * HH + ch * 8];
        }
    }
}

// ---------------- final: out[i] = b4 + z[i]*dinv^2 + sum z[src]*w ----------------

__global__ __launch_bounds__(256) void final_kernel(const float* __restrict__ z,
                                                    const int2* __restrict__ csr,
                                                    const int* __restrict__ rowstart,
                                                    const float* __restrict__ dinv,
                                                    const float* __restrict__ b4,
                                                    float* __restrict__ out) {
    int i = blockIdx.x * 256 + threadIdx.x;
    if (i >= NN) return;
    float acc = z[i] * dinv[i] * dinv[i] + b4[0];
    int e0 = rowstart[i], e1 = rowstart[i + 1];
    int el = e1 - 1;
    for (int e = e0; e < e1; e += 8) {
        int idx[8];
        #pragma unroll
        for (int j = 0; j < 8; j++) idx[j] = (e + j < e1) ? e + j : el;
        int2 d[8];
        #pragma unroll
        for (int j = 0; j < 8; j++) d[j] = ldnt2(&csr[idx[j]]);
        float zv[8];
        #pragma unroll
        for (int j = 0; j < 8; j++) zv[j] = z[d[j].x];
        #pragma unroll
        for (int j = 0; j < 8; j++) {
            float w = (e + j < e1) ? __int_as_float(d[j].y) : 0.0f;
            acc += zv[j] * w;
        }
    }
    out[i] = acc;
}

// ---------------- launch ----------------

static inline size_t align256(size_t x) { return (x + 255) & ~(size_t)255; }

extern "C" void kernel_launch(void* const* d_in, const int* in_sizes, int n_in,
                              void* d_out, int out_size, void* d_ws, size_t ws_size,
                              hipStream_t stream) {
    const float* x   = (const float*)d_in[0];
    const int*   ei  = (const int*)d_in[1];
    const int*   src = ei;
    const int*   dst = ei + EE;
    const float* W1 = (const float*)d_in[2];
    const float* b1 = (const float*)d_in[3];
    const float* g1 = (const float*)d_in[4];
    const float* be1 = (const float*)d_in[5];
    const float* m1 = (const float*)d_in[6];
    const float* v1 = (const float*)d_in[7];
    const float* W2 = (const float*)d_in[8];
    const float* b2 = (const float*)d_in[9];
    const float* g2 = (const float*)d_in[10];
    const float* be2 = (const float*)d_in[11];
    const float* m2 = (const float*)d_in[12];
    const float* v2 = (const float*)d_in[13];
    const float* W3 = (const float*)d_in[14];
    const float* b3 = (const float*)d_in[15];
    const float* g3 = (const float*)d_in[16];
    const float* be3 = (const float*)d_in[17];
    const float* m3 = (const float*)d_in[18];
    const float* v3 = (const float*)d_in[19];
    const float* W4 = (const float*)d_in[20];
    const float* b4 = (const float*)d_in[21];

    char* wp = (char*)d_ws;
    int*   deg      = (int*)wp;        wp += align256((size_t)NN * 4);
    int*   blksum   = (int*)wp;        wp += align256(512 * 4);
    int*   rowstart = (int*)wp;        wp += align256((size_t)(NN + 1) * 4);
    int*   cursor   = (int*)wp;        wp += align256((size_t)NN * 4);
    float* dinv     = (float*)wp;      wp += align256((size_t)NN * 4);
    int2*  csr      = (int2*)wp;       wp += align256((size_t)EE * 8);
    float* z        = (float*)wp;      wp += align256((size_t)NN * 4);
    float* zres     = (float*)wp;      wp += align256((size_t)NN * 4);
    u16*   wt1      = (u16*)wp;        wp += align256((size_t)HH * FIN * 2);
    u16*   wt2      = (u16*)wp;        wp += align256((size_t)HH * HH * 2);
    u16*   wt3      = (u16*)wp;        wp += align256((size_t)HH * HH * 2);
    u16*   xb       = (u16*)wp;        wp += align256((size_t)NN * FIN * 2);
    u16*   x1       = (u16*)wp;        wp += align256((size_t)NN * HH * 2);
    u16*   x2       = (u16*)wp;        wp += align256((size_t)NN * HH * 2);
    u16*   bufA     = (u16*)wp;        wp += align256((size_t)NN * HH * 2);

    float* outp = (float*)d_out;

    // ---- setup + CSR build (no hipMemsetAsync)
    setup_kernel<<<(NN * FIN / 8 + 255) / 256, 256, 0, stream>>>(
        x, xb, deg, W1, W2, W3, wt1, wt2, wt3);
    hist_kernel<<<(EE + 255) / 256, 256, 0, stream>>>(dst, deg);
    scan1_kernel<<<NB, 256, 0, stream>>>(deg, rowstart, blksum, dinv);
    scan23_kernel<<<(NN + 511) / 512, 512, 0, stream>>>(rowstart, blksum, cursor);
    fill_kernel<<<(EE + 255) / 256, 256, 0, stream>>>(src, dst, dinv, cursor, csr);

    // ---- layer 1: agg(xb) -> bufA; GEMM 64->128 + BN + ReLU -> x1, zres = x1 . W4
    agg64_kernel<<<(NN + 31) / 32, 256, 0, stream>>>(xb, csr, rowstart, dinv, bufA);
    gemm_bn_relu<FIN, 1><<<(NN + 127) / 128, 256, 0, stream>>>(
        bufA, wt1, b1, g1, be1, m1, v1, x1, W4, zres, nullptr);

    // ---- layer 2: agg(x1) -> bufA; GEMM + BN + ReLU -> x2
    agg128_kernel<<<(NN + 15) / 16, 256, 0, stream>>>(x1, csr, rowstart, dinv, bufA);
    gemm_bn_relu<HH, 0><<<(NN + 127) / 128, 256, 0, stream>>>(
        bufA, wt2, b2, g2, be2, m2, v2, x2, nullptr, nullptr, nullptr);

    // ---- layer 3: agg(x2) -> bufA; GEMM + BN + ReLU, fused z = C.W4 + zres
    agg128_kernel<<<(NN + 15) / 16, 256, 0, stream>>>(x2, csr, rowstart, dinv, bufA);
    gemm_bn_relu<HH, 2><<<(NN + 127) / 128, 256, 0, stream>>>(
        bufA, wt3, b3, g3, be3, m3, v3, nullptr, W4, zres, z);

    // ---- final aggregation of scalars
    final_kernel<<<(NN + 255) / 256, 256, 0, stream>>>(z, csr, rowstart, dinv, b4, outp);
}

// Round 20
// 225.883 us; speedup vs baseline: 1.0827x; 1.0827x over previous
//
#include <hip/hip_runtime.h>

#define NN 100000
#define EE 500000
#define FIN 64
#define HH 128
#define BN_EPS 1e-5f
#define NB ((NN + 255) / 256)   // 391 scan blocks

typedef unsigned short u16;
typedef unsigned long long u64;
typedef short bf16x8 __attribute__((ext_vector_type(8)));
typedef float f32x4 __attribute__((ext_vector_type(4)));

__device__ __forceinline__ u16 f2bf(float f) {
    unsigned int u = __float_as_uint(f);
    u = (u + 0x7FFFu + ((u >> 16) & 1u)) >> 16;   // round-to-nearest-even
    return (u16)u;
}
__device__ __forceinline__ float bf2f(u16 u) {
    return __uint_as_float((unsigned int)u << 16);
}
// nontemporal int2 load (csr entries are read exactly once per pass)
__device__ __forceinline__ int2 ldnt2(const int2* p) {
    u64 v = __builtin_nontemporal_load((const u64*)p);
    int2 r;
    r.x = (int)(unsigned)(v & 0xFFFFFFFFull);
    r.y = (int)(unsigned)(v >> 32);
    return r;
}
// accumulate 8 bf16 (packed in uint4) * w into a[0..7]
__device__ __forceinline__ void fma8(float* a, uint4 s, float w) {
    a[0] += bf2f((u16)(s.x & 0xFFFF)) * w;
    a[1] += bf2f((u16)(s.x >> 16))    * w;
    a[2] += bf2f((u16)(s.y & 0xFFFF)) * w;
    a[3] += bf2f((u16)(s.y >> 16))    * w;
    a[4] += bf2f((u16)(s.z & 0xFFFF)) * w;
    a[5] += bf2f((u16)(s.z >> 16))    * w;
    a[6] += bf2f((u16)(s.w & 0xFFFF)) * w;
    a[7] += bf2f((u16)(s.w >> 16))    * w;
}
__device__ __forceinline__ uint4 pack8(const float* a) {
    uint4 o;
    o.x = (unsigned)f2bf(a[0]) | ((unsigned)f2bf(a[1]) << 16);
    o.y = (unsigned)f2bf(a[2]) | ((unsigned)f2bf(a[3]) << 16);
    o.z = (unsigned)f2bf(a[4]) | ((unsigned)f2bf(a[5]) << 16);
    o.w = (unsigned)f2bf(a[6]) | ((unsigned)f2bf(a[7]) << 16);
    return o;
}
// 64-lane inclusive scan via shfl_up
__device__ __forceinline__ int wave_iscan(int v, int lane) {
    #pragma unroll
    for (int off = 1; off < 64; off <<= 1) {
        int n = __shfl_up(v, off, 64);
        if (lane >= off) v += n;
    }
    return v;
}

// ---------------- setup: x->bf16, zero deg, all W -> Wt bf16 transposed ----------------

__global__ __launch_bounds__(256) void setup_kernel(const float* __restrict__ x,
                                                    u16* __restrict__ xb,
                                                    int* __restrict__ deg,
                                                    const float* __restrict__ W1,
                                                    const float* __restrict__ W2,
                                                    const float* __restrict__ W3,
                                                    u16* __restrict__ wt1,
                                                    u16* __restrict__ wt2,
                                                    u16* __restrict__ wt3) {
    int i = blockIdx.x * 256 + threadIdx.x;
    if (i < NN) deg[i] = 0;
    if (i < HH * FIN) {
        int n = i / FIN, k = i - n * FIN;
        wt1[i] = f2bf(W1[(size_t)k * HH + n]);
    }
    if (i < HH * HH) {
        int n = i >> 7, k = i & 127;
        wt2[i] = f2bf(W2[(size_t)k * HH + n]);
        wt3[i] = f2bf(W3[(size_t)k * HH + n]);
    }
    if (i < NN * FIN / 8) {
        float4 f0 = ((const float4*)x)[i * 2];
        float4 f1 = ((const float4*)x)[i * 2 + 1];
        uint4 o;
        o.x = (unsigned)f2bf(f0.x) | ((unsigned)f2bf(f0.y) << 16);
        o.y = (unsigned)f2bf(f0.z) | ((unsigned)f2bf(f0.w) << 16);
        o.z = (unsigned)f2bf(f1.x) | ((unsigned)f2bf(f1.y) << 16);
        o.w = (unsigned)f2bf(f1.z) | ((unsigned)f2bf(f1.w) << 16);
        ((uint4*)xb)[i] = o;
    }
}

// ---------------- CSR build ----------------

__global__ __launch_bounds__(256) void hist_kernel(const int* __restrict__ dst,
                                                   int* __restrict__ deg) {
    int e = blockIdx.x * 256 + threadIdx.x;
    if (e < EE) atomicAdd(&deg[__builtin_nontemporal_load(&dst[e])], 1);
}

// per-block exclusive scan + dinv (wave-level shfl scan, 1 barrier)
__global__ __launch_bounds__(256) void scan1_kernel(const int* __restrict__ deg,
                                                    int* __restrict__ rowstart,
                                                    int* __restrict__ blksum,
                                                    float* __restrict__ dinv) {
    __shared__ int wsum[4];
    int t = threadIdx.x;
    int lane = t & 63;
    int wv = t >> 6;
    int i = blockIdx.x * 256 + t;
    int v = (i < NN) ? deg[i] : 0;
    if (i < NN) dinv[i] = rsqrtf((float)v + 1.0f);
    int inc = wave_iscan(v, lane);
    if (lane == 63) wsum[wv] = inc;
    __syncthreads();
    int pre = 0;
    #pragma unroll
    for (int w = 0; w < 4; w++) pre += (w < wv) ? wsum[w] : 0;
    inc += pre;
    if (i < NN) rowstart[i] = inc - v;
    if (t == 255) blksum[blockIdx.x] = inc;
}

// scan of blksum (redundant per block, wave-level) + apply to rowstart/cursor
__global__ __launch_bounds__(512) void scan23_kernel(int* __restrict__ rowstart,
                                                     const int* __restrict__ blksum,
                                                     int* __restrict__ cursor) {
    __shared__ int wsum[8];
    __shared__ int ex[512];
    int t = threadIdx.x;
    int lane = t & 63;
    int wv = t >> 6;
    int vv = (t < NB) ? blksum[t] : 0;
    int inc = wave_iscan(vv, lane);
    if (lane == 63) wsum[wv] = inc;
    __syncthreads();
    int pre = 0;
    #pragma unroll
    for (int w = 0; w < 8; w++) pre += (w < wv) ? wsum[w] : 0;
    ex[t] = inc + pre - vv;
    __syncthreads();
    int i = blockIdx.x * 512 + t;
    if (i < NN) {
        int r = rowstart[i] + ex[i >> 8];
        rowstart[i] = r;
        cursor[i] = r;
    }
    if (i == 0) rowstart[NN] = EE;
}

__global__ __launch_bounds__(256) void fill_kernel(const int* __restrict__ src,
                                                   const int* __restrict__ dst,
                                                   const float* __restrict__ dinv,
                                                   int* __restrict__ cursor,
                                                   int2* __restrict__ csr) {
    int e = blockIdx.x * 256 + threadIdx.x;
    if (e >= EE) return;
    int s = __builtin_nontemporal_load(&src[e]);
    int d = __builtin_nontemporal_load(&dst[e]);
    float nm = dinv[s] * dinv[d];
    int pos = atomicAdd(&cursor[d], 1);
    csr[pos] = make_int2(s, __float_as_int(nm));   // L2-cached store (re-read 4x)
}

// ---------------- gather aggregation (bf16 in/out, fp32 accumulate) ----------------
// 16-lane group per node; predicated full rounds of 8 gathers (clamped index,
// zero weight for OOB): P(deg<=8)=0.93 -> ~1.07 serial rounds per node.

__global__ __launch_bounds__(256) void agg128_kernel(const u16* __restrict__ x,
                                                     const int2* __restrict__ csr,
                                                     const int* __restrict__ rowstart,
                                                     const float* __restrict__ dinv,
                                                     u16* __restrict__ out) {
    int gid = blockIdx.x * 16 + (threadIdx.x >> 4);
    int lane = threadIdx.x & 15;
    if (gid >= NN) return;
    float sn = dinv[gid];
    sn *= sn;
    const uint4* xp = (const uint4*)x;   // row = 16 x uint4 (8 bf16 each)
    float a[8] = {0, 0, 0, 0, 0, 0, 0, 0};
    fma8(a, xp[(size_t)gid * 16 + lane], sn);
    int e0 = rowstart[gid], e1 = rowstart[gid + 1];
    int el = e1 - 1;
    for (int e = e0; e < e1; e += 8) {
        int idx[8];
        #pragma unroll
        for (int j = 0; j < 8; j++) idx[j] = (e + j < e1) ? e + j : el;
        int2 d[8];
        #pragma unroll
        for (int j = 0; j < 8; j++) d[j] = ldnt2(&csr[idx[j]]);
        uint4 s[8];
        #pragma unroll
        for (int j = 0; j < 8; j++) s[j] = xp[(size_t)d[j].x * 16 + lane];
        #pragma unroll
        for (int j = 0; j < 8; j++) {
            float w = (e + j < e1) ? __int_as_float(d[j].y) : 0.0f;
            fma8(a, s[j], w);
        }
    }
    ((uint4*)out)[(size_t)gid * 16 + lane] = pack8(a);
}

__global__ __launch_bounds__(256) void agg64_kernel(const u16* __restrict__ x,
                                                    const int2* __restrict__ csr,
                                                    const int* __restrict__ rowstart,
                                                    const float* __restrict__ dinv,
                                                    u16* __restrict__ out) {
    int gid = blockIdx.x * 32 + (threadIdx.x >> 3);
    int lane = threadIdx.x & 7;
    if (gid >= NN) return;
    float sn = dinv[gid];
    sn *= sn;
    const uint4* xp = (const uint4*)x;   // row = 8 x uint4 (8 bf16 each)
    float a[8] = {0, 0, 0, 0, 0, 0, 0, 0};
    fma8(a, xp[(size_t)gid * 8 + lane], sn);
    int e0 = rowstart[gid], e1 = rowstart[gid + 1];
    int el = e1 - 1;
    for (int e = e0; e < e1; e += 8) {
        int idx[8];
        #pragma unroll
        for (int j = 0; j < 8; j++) idx[j] = (e + j < e1) ? e + j : el;
        int2 d[8];
        #pragma unroll
        for (int j = 0; j < 8; j++) d[j] = ldnt2(&csr[idx[j]]);
        uint4 s[8];
        #pragma unroll
        for (int j = 0; j < 8; j++) s[j] = xp[(size_t)d[j].x * 8 + lane];
        #pragma unroll
        for (int j = 0; j < 8; j++) {
            float w = (e + j < e1) ? __int_as_float(d[j].y) : 0.0f;
            fma8(a, s[j], w);
        }
    }
    ((uint4*)out)[(size_t)gid * 8 + lane] = pack8(a);
}

// ---------------- MFMA GEMM + bias + BN(eval) + ReLU ----------------
// BM=128: 4 waves, each wave owns 32 rows (2x 16-row tiles) -> B-frags shared
// across both tiles. Epilogue via LDS -> coalesced uint4 stores (MODE<2).
// MODE 0: store C.  MODE 1: store C and zres[row] = dot(C_row, W4).
// MODE 2: no C store, no LDS; z[row] = dot(C_row, W4) + zres[row].

template<int K, int MODE>
__global__ __launch_bounds__(256) void gemm_bn_relu(const u16* __restrict__ A,
                                                    const u16* __restrict__ Wt,
                                                    const float* __restrict__ bias,
                                                    const float* __restrict__ g,
                                                    const float* __restrict__ be,
                                                    const float* __restrict__ m,
                                                    const float* __restrict__ v,
                                                    u16* __restrict__ out,
                                                    const float* __restrict__ W4,
                                                    float* __restrict__ zres,
                                                    float* __restrict__ z) {
    __shared__ u16 Csm[(MODE < 2) ? 128 * HH : 16];   // 32 KB when storing C

    int tid = threadIdx.x;
    int wave = tid >> 6;
    int lane = tid & 63;
    int lrow = lane & 15;
    int kgrp = lane >> 4;

    int blk0 = blockIdx.x * 128;
    int w0r = blk0 + wave * 32;            // wave's first row (2 tiles of 16)
    int ar0 = w0r + lrow;       if (ar0 >= NN) ar0 = NN - 1;
    int ar1 = w0r + 16 + lrow;  if (ar1 >= NN) ar1 = NN - 1;

    f32x4 acc[2][8];
    #pragma unroll
    for (int t = 0; t < 2; t++)
        #pragma unroll
        for (int ct = 0; ct < 8; ct++) acc[t][ct] = (f32x4){0.f, 0.f, 0.f, 0.f};

    #pragma unroll
    for (int kc = 0; kc < K / 32; kc++) {
        bf16x8 afr0 = *(const bf16x8*)&A[(size_t)ar0 * K + kc * 32 + kgrp * 8];
        bf16x8 afr1 = *(const bf16x8*)&A[(size_t)ar1 * K + kc * 32 + kgrp * 8];
        #pragma unroll
        for (int ct = 0; ct < 8; ct++) {
            bf16x8 bfr = *(const bf16x8*)&Wt[(size_t)(ct * 16 + lrow) * K + kc * 32 + kgrp * 8];
            acc[0][ct] = __builtin_amdgcn_mfma_f32_16x16x32_bf16(afr0, bfr, acc[0][ct], 0, 0, 0);
            acc[1][ct] = __builtin_amdgcn_mfma_f32_16x16x32_bf16(afr1, bfr, acc[1][ct], 0, 0, 0);
        }
    }

    // BN scale/shift for this lane's 8 columns (col = ct*16 + lrow)
    float sc[8], sh[8];
    #pragma unroll
    for (int ct = 0; ct < 8; ct++) {
        int col = ct * 16 + lrow;
        float s = g[col] * rsqrtf(v[col] + BN_EPS);
        sc[ct] = s;
        sh[ct] = (bias[col] - m[col]) * s + be[col];
    }

    float w4[8];
    if constexpr (MODE >= 1) {
        #pragma unroll
        for (int ct = 0; ct < 8; ct++) w4[ct] = W4[ct * 16 + lrow];
    }

    int rbase = kgrp * 4;   // C layout: row = tile0 + rbase + r, col = ct*16 + lrow
    #pragma unroll
    for (int t = 0; t < 2; t++) {
        #pragma unroll
        for (int r = 0; r < 4; r++) {
            int lr = wave * 32 + t * 16 + rbase + r;
            int row = blk0 + lr;
            float part = 0.0f;
            #pragma unroll
            for (int ct = 0; ct < 8; ct++) {
                float val = fmaxf(acc[t][ct][r] * sc[ct] + sh[ct], 0.0f);
                if constexpr (MODE < 2)
                    Csm[lr * HH + ct * 16 + lrow] = f2bf(val);
                if constexpr (MODE >= 1)
                    part += val * w4[ct];
            }
            if constexpr (MODE >= 1) {
                #pragma unroll
                for (int off = 1; off < 16; off <<= 1)
                    part += __shfl_xor(part, off, 16);
                if (lrow == 0 && row < NN) {
                    if constexpr (MODE == 1) zres[row] = part;
                    else                     z[row] = part + zres[row];
                }
            }
        }
    }

    if constexpr (MODE < 2) {
        __syncthreads();
        // coalesced writeback: 128 rows x 128 cols bf16 = 32 KB, uint4 x8 per thread
        #pragma unroll
        for (int it = 0; it < 8; it++) {
            int id = it * 256 + tid;
            int lr = id >> 4;
            int ch = id & 15;
            int row = blk0 + lr;
            if (row < NN)
                *(uint4*)&out[(size_t)row * HH + ch * 8] =
                    *(const uint4*)&Csm[lr * HH + ch * 8];
        }
    }
}

// ---------------- final: out[i] = b4 + z[i]*dinv^2 + sum z[src]*w ----------------
// predicated rounds of 8 scalar gathers (no serial remainder tail)

__global__ __launch_bounds__(256) void final_kernel(const float* __restrict__ z,
                                                    const int2* __restrict__ csr,
                                                    const int* __restrict__ rowstart,
                                                    const float* __restrict__ dinv,
                                                    const float* __restrict__ b4,
                                                    float* __restrict__ out) {
    int i = blockIdx.x * 256 + threadIdx.x;
    if (i >= NN) return;
    float acc = z[i] * dinv[i] * dinv[i] + b4[0];
    int e0 = rowstart[i], e1 = rowstart[i + 1];
    int el = e1 - 1;
    for (int e = e0; e < e1; e += 8) {
        int idx[8];
        #pragma unroll
        for (int j = 0; j < 8; j++) idx[j] = (e + j < e1) ? e + j : el;
        int2 d[8];
        #pragma unroll
        for (int j = 0; j < 8; j++) d[j] = ldnt2(&csr[idx[j]]);
        float zv[8];
        #pragma unroll
        for (int j = 0; j < 8; j++) zv[j] = z[d[j].x];
        #pragma unroll
        for (int j = 0; j < 8; j++) {
            float w = (e + j < e1) ? __int_as_float(d[j].y) : 0.0f;
            acc += zv[j] * w;
        }
    }
    out[i] = acc;
}

// ---------------- launch ----------------

static inline size_t align256(size_t x) { return (x + 255) & ~(size_t)255; }

extern "C" void kernel_launch(void* const* d_in, const int* in_sizes, int n_in,
                              void* d_out, int out_size, void* d_ws, size_t ws_size,
                              hipStream_t stream) {
    const float* x   = (const float*)d_in[0];
    const int*   ei  = (const int*)d_in[1];
    const int*   src = ei;
    const int*   dst = ei + EE;
    const float* W1 = (const float*)d_in[2];
    const float* b1 = (const float*)d_in[3];
    const float* g1 = (const float*)d_in[4];
    const float* be1 = (const float*)d_in[5];
    const float* m1 = (const float*)d_in[6];
    const float* v1 = (const float*)d_in[7];
    const float* W2 = (const float*)d_in[8];
    const float* b2 = (const float*)d_in[9];
    const float* g2 = (const float*)d_in[10];
    const float* be2 = (const float*)d_in[11];
    const float* m2 = (const float*)d_in[12];
    const float* v2 = (const float*)d_in[13];
    const float* W3 = (const float*)d_in[14];
    const float* b3 = (const float*)d_in[15];
    const float* g3 = (const float*)d_in[16];
    const float* be3 = (const float*)d_in[17];
    const float* m3 = (const float*)d_in[18];
    const float* v3 = (const float*)d_in[19];
    const float* W4 = (const float*)d_in[20];
    const float* b4 = (const float*)d_in[21];

    char* wp = (char*)d_ws;
    int*   deg      = (int*)wp;        wp += align256((size_t)NN * 4);
    int*   blksum   = (int*)wp;        wp += align256(512 * 4);
    int*   rowstart = (int*)wp;        wp += align256((size_t)(NN + 1) * 4);
    int*   cursor   = (int*)wp;        wp += align256((size_t)NN * 4);
    float* dinv     = (float*)wp;      wp += align256((size_t)NN * 4);
    int2*  csr      = (int2*)wp;       wp += align256((size_t)EE * 8);
    float* z        = (float*)wp;      wp += align256((size_t)NN * 4);
    float* zres     = (float*)wp;      wp += align256((size_t)NN * 4);
    u16*   wt1      = (u16*)wp;        wp += align256((size_t)HH * FIN * 2);
    u16*   wt2      = (u16*)wp;        wp += align256((size_t)HH * HH * 2);
    u16*   wt3      = (u16*)wp;        wp += align256((size_t)HH * HH * 2);
    u16*   xb       = (u16*)wp;        wp += align256((size_t)NN * FIN * 2);
    u16*   x1       = (u16*)wp;        wp += align256((size_t)NN * HH * 2);
    u16*   x2       = (u16*)wp;        wp += align256((size_t)NN * HH * 2);
    u16*   bufA     = (u16*)wp;        wp += align256((size_t)NN * HH * 2);
    u16*   bufB     = (u16*)wp;        wp += align256((size_t)NN * HH * 2);

    float* outp = (float*)d_out;

    // ---- setup + CSR build (no hipMemsetAsync)
    setup_kernel<<<(NN * FIN / 8 + 255) / 256, 256, 0, stream>>>(
        x, xb, deg, W1, W2, W3, wt1, wt2, wt3);
    hist_kernel<<<(EE + 255) / 256, 256, 0, stream>>>(dst, deg);
    scan1_kernel<<<NB, 256, 0, stream>>>(deg, rowstart, blksum, dinv);
    scan23_kernel<<<(NN + 511) / 512, 512, 0, stream>>>(rowstart, blksum, cursor);
    fill_kernel<<<(EE + 255) / 256, 256, 0, stream>>>(src, dst, dinv, cursor, csr);

    // ---- layer 1: agg(xb) -> bufA; GEMM 64->128 + BN + ReLU -> x1, zres = x1 . W4
    agg64_kernel<<<(NN + 31) / 32, 256, 0, stream>>>(xb, csr, rowstart, dinv, bufA);
    gemm_bn_relu<FIN, 1><<<(NN + 127) / 128, 256, 0, stream>>>(
        bufA, wt1, b1, g1, be1, m1, v1, x1, W4, zres, nullptr);

    // ---- layer 2: agg(x1) -> bufB; GEMM + BN + ReLU -> x2
    agg128_kernel<<<(NN + 15) / 16, 256, 0, stream>>>(x1, csr, rowstart, dinv, bufB);
    gemm_bn_relu<HH, 0><<<(NN + 127) / 128, 256, 0, stream>>>(
        bufB, wt2, b2, g2, be2, m2, v2, x2, nullptr, nullptr, nullptr);

    // ---- layer 3: agg(x2) -> bufA; GEMM + BN + ReLU, fused z = C.W4 + zres
    agg128_kernel<<<(NN + 15) / 16, 256, 0, stream>>>(x2, csr, rowstart, dinv, bufA);
    gemm_bn_relu<HH, 2><<<(NN + 127) / 128, 256, 0, stream>>>(
        bufA, wt3, b3, g3, be3, m3, v3, nullptr, W4, zres, z);

    // ---- final aggregation of scalars
    final_kernel<<<(NN + 255) / 256, 256, 0, stream>>>(z, csr, rowstart, dinv, b4, outp);
}